// Round 10
// baseline (273.652 us; speedup 1.0000x reference)
//
#include <hip/hip_runtime.h>

#define T_STEPS 128
#define CIN     16
#define HH      64
#define WW      64
#define COUT    64
#define HWSZ    (HH * WW)          // 4096
#define CHW     (COUT * HWSZ)      // 262144
#define XCHW    (CIN * HWSZ)       // 65536

// pass-1: block = one t, 16x32 tile, all 64 co. 8 waves; wave owns an 8-co
// set (72 w floats/ci via s_load). Thread = 1x8 spatial patch, ky-major.
// HARD CONSTRAINT (measured R8/R9): VGPR must stay <=64 — acc[8][8] lives in
// 64 AGPRs; unified budget 128 = exactly 2 blocks/CU (16 waves). VGPR 68 in
// R9 -> 1 block/CU, -12 us. No experiment may add VGPR pressure.
// unroll 2 on ci: scheduler overlaps ci+1's s_loads/ds_reads under ci's FMA
// tail without extra named registers.
#define TILEH   16
#define TILEW   32
#define HALOH   18
#define HALOW   34
#define LSTR    36                    // padded LDS row stride (floats)
#define PLANE   (HALOH * LSTR)        // 648 floats per ci
#define NST     (CIN * HALOH * HALOW) // 9792 staged elements
#define WBLK    40                    // padded weight block per (co-group-of-4, ci)

typedef float vfloat4 __attribute__((ext_vector_type(4)));  // native vec for NT ld/st

// ---- setup: W[64][16][3][3] -> Wtr[(co>>2)*16+ci][40], inner (co&3)*9+k ----
__global__ void transpose_w(const float* __restrict__ W, float* __restrict__ Wtr) {
    int e = blockIdx.x * 256 + threadIdx.x;     // 0..9215
    if (e >= COUT * CIN * 9) return;
    int co = e / (CIN * 9);
    int r  = e - co * (CIN * 9);
    int ci = r / 9;
    int k  = r - ci * 9;
    Wtr[((co >> 2) * CIN + ci) * WBLK + (co & 3) * 9 + k] = W[e];
}

__global__ __launch_bounds__(512, 2)
void spiking_conv_pass1(const float* __restrict__ x, const float* __restrict__ Wtr,
                        const float* __restrict__ b, float* __restrict__ out) {
    __shared__ float xs[CIN * PLANE];   // 41472 B

    const int tid = threadIdx.x;        // 0..511
    const int t   = blockIdx.y;
    const int h0  = (blockIdx.x >> 1) * TILEH;   // 4 row-bands
    const int w0  = (blockIdx.x & 1) * TILEW;    // 2 col-halves

    // ---- stage all 16 ci (+halo) once: 9792 elements, 2 batches of 10 ----
    const float* xt = x + t * XCHW;
    {
        float vbuf[10]; int ibuf[10];
#pragma unroll
        for (int k = 0; k < 10; ++k) {
            unsigned e = tid + k * 512;
            unsigned ci = e / (HALOH * HALOW);
            unsigned rem = e - ci * (HALOH * HALOW);
            unsigned r  = rem / HALOW;
            unsigned c  = rem - r * HALOW;
            int gh = h0 - 1 + (int)r;
            int gw = w0 - 1 + (int)c;
            bool inb = (unsigned)gh < HH && (unsigned)gw < WW;
            vbuf[k] = inb ? xt[ci * HWSZ + gh * WW + gw] : 0.f;
            ibuf[k] = ci * PLANE + r * LSTR + c;
        }
#pragma unroll
        for (int k = 0; k < 10; ++k) xs[ibuf[k]] = vbuf[k];
#pragma unroll
        for (int k = 0; k < 10; ++k) {
            unsigned e = tid + (10 + k) * 512;
            unsigned ci = e / (HALOH * HALOW);
            unsigned rem = e - ci * (HALOH * HALOW);
            unsigned r  = rem / HALOW;
            unsigned c  = rem - r * HALOW;
            int gh = h0 - 1 + (int)r;
            int gw = w0 - 1 + (int)c;
            bool inb = e < NST && (unsigned)gh < HH && (unsigned)gw < WW;
            vbuf[k] = inb ? xt[ci * HWSZ + gh * WW + gw] : 0.f;
            ibuf[k] = (e < NST) ? (int)(ci * PLANE + r * LSTR + c) : -1;
        }
#pragma unroll
        for (int k = 0; k < 10; ++k)
            if (ibuf[k] >= 0) xs[ibuf[k]] = vbuf[k];
    }
    __syncthreads();

    // ---- compute: wave = one 8-co set; thread = 1x8 patch ----
    const int cog = __builtin_amdgcn_readfirstlane(tid >> 6);  // 0..7 (one per wave)
    const int ln  = tid & 63;
    const int pr0 = ln >> 2;            // 0..15
    const int pc0 = (ln & 3) * 8;       // 0,8,16,24
    float* outt = out + t * CHW;

    float acc[8][8];
#pragma unroll
    for (int j = 0; j < 8; ++j)
#pragma unroll
        for (int p = 0; p < 8; ++p) acc[j][p] = 0.f;

#pragma unroll 2
    for (int ci = 0; ci < CIN; ++ci) {
        // both 36-float w blocks for this wave's 8 co: SGPR-resident.
        const float* wb0 = Wtr + ((cog * 2 + 0) * CIN + ci) * WBLK;
        const float* wb1 = Wtr + ((cog * 2 + 1) * CIN + ci) * WBLK;
        float w0[36], w1[36];
#pragma unroll
        for (int i = 0; i < 36; ++i) w0[i] = wb0[i];
#pragma unroll
        for (int i = 0; i < 36; ++i) w1[i] = wb1[i];

        // ky-major: one LDS row (10 floats) live at a time. Accumulate order
        // per output is (ci, ky, kx) -> bit-identical to reference order.
#pragma unroll
        for (int ky = 0; ky < 3; ++ky) {
            const float* row = &xs[ci * PLANE + (pr0 + ky) * LSTR + pc0];
            float4 a  = *(const float4*)row;
            float4 b4 = *(const float4*)(row + 4);
            float2 c2 = *(const float2*)(row + 8);
            float xv[10];
            xv[0] = a.x;  xv[1] = a.y;  xv[2] = a.z;  xv[3] = a.w;
            xv[4] = b4.x; xv[5] = b4.y; xv[6] = b4.z; xv[7] = b4.w;
            xv[8] = c2.x; xv[9] = c2.y;
#pragma unroll
            for (int jj = 0; jj < 4; ++jj)
#pragma unroll
                for (int kx = 0; kx < 3; ++kx) {
                    const float wv = w0[jj * 9 + ky * 3 + kx];
#pragma unroll
                    for (int p = 0; p < 8; ++p)
                        acc[jj][p] += wv * xv[kx + p];
                }
#pragma unroll
            for (int jj = 0; jj < 4; ++jj)
#pragma unroll
                for (int kx = 0; kx < 3; ++kx) {
                    const float wv = w1[jj * 9 + ky * 3 + kx];
#pragma unroll
                    for (int p = 0; p < 8; ++p)
                        acc[4 + jj][p] += wv * xv[kx + p];
                }
        }
    }

    // ---- epilogue: +bias, 2x float4 stores per co ----
#pragma unroll
    for (int g = 0; g < 2; ++g)
#pragma unroll
        for (int jj = 0; jj < 4; ++jj) {
            const int co = cog * 8 + g * 4 + jj;
            const float bias = b[co];
            float* op = &outt[co * HWSZ + (h0 + pr0) * WW + (w0 + pc0)];
            float4 o0, o1;
            o0.x = acc[g * 4 + jj][0] + bias;
            o0.y = acc[g * 4 + jj][1] + bias;
            o0.z = acc[g * 4 + jj][2] + bias;
            o0.w = acc[g * 4 + jj][3] + bias;
            o1.x = acc[g * 4 + jj][4] + bias;
            o1.y = acc[g * 4 + jj][5] + bias;
            o1.z = acc[g * 4 + jj][6] + bias;
            o1.w = acc[g * 4 + jj][7] + bias;
            *(float4*)op = o0;
            *(float4*)(op + 4) = o1;
        }
}

// Scan, float4-batch, src/dst split, fully nontemporal: conv reads are
// stream-once (never reused) -> NT loads skip L1/L2 allocation (L3 lookups
// still hit resident data); spike writes NT to d_out. src==dst stays the
// safe in-place fallback.
__global__ __launch_bounds__(256)
void spiking_scan_pass2(const float* __restrict__ src, float* __restrict__ dst) {
    const int idx = blockIdx.x * 256 + threadIdx.x;   // 0..65535
    const vfloat4* ps = (const vfloat4*)src + idx;    // column stride CHW/4
    vfloat4* pd = (vfloat4*)dst + idx;
    float sx = 0.f, sy = 0.f, sz = 0.f, sw = 0.f;
    vfloat4 v[8], nv[8];
#pragma unroll
    for (int i = 0; i < 8; ++i) v[i] = __builtin_nontemporal_load(&ps[(size_t)i * (CHW / 4)]);
#pragma unroll 1
    for (int tb = 0; tb < 15; ++tb) {
#pragma unroll
        for (int i = 0; i < 8; ++i) nv[i] = __builtin_nontemporal_load(&ps[(size_t)((tb + 1) * 8 + i) * (CHW / 4)]);
#pragma unroll
        for (int i = 0; i < 8; ++i) {
            vfloat4 o;
            sx += v[i].x; bool a0 = (sx >= 8.0f); o.x = a0 ? 1.f : 0.f; sx = a0 ? 0.f : sx; sx = fmaxf(sx, -1.f);
            sy += v[i].y; bool a1 = (sy >= 8.0f); o.y = a1 ? 1.f : 0.f; sy = a1 ? 0.f : sy; sy = fmaxf(sy, -1.f);
            sz += v[i].z; bool a2 = (sz >= 8.0f); o.z = a2 ? 1.f : 0.f; sz = a2 ? 0.f : sz; sz = fmaxf(sz, -1.f);
            sw += v[i].w; bool a3 = (sw >= 8.0f); o.w = a3 ? 1.f : 0.f; sw = a3 ? 0.f : sw; sw = fmaxf(sw, -1.f);
            __builtin_nontemporal_store(o, &pd[(size_t)(tb * 8 + i) * (CHW / 4)]);
        }
#pragma unroll
        for (int i = 0; i < 8; ++i) v[i] = nv[i];
    }
#pragma unroll
    for (int i = 0; i < 8; ++i) {
        vfloat4 o;
        sx += v[i].x; bool a0 = (sx >= 8.0f); o.x = a0 ? 1.f : 0.f; sx = a0 ? 0.f : sx; sx = fmaxf(sx, -1.f);
        sy += v[i].y; bool a1 = (sy >= 8.0f); o.y = a1 ? 1.f : 0.f; sy = a1 ? 0.f : sy; sy = fmaxf(sy, -1.f);
        sz += v[i].z; bool a2 = (sz >= 8.0f); o.z = a2 ? 1.f : 0.f; sz = a2 ? 0.f : sz; sz = fmaxf(sz, -1.f);
        sw += v[i].w; bool a3 = (sw >= 8.0f); o.w = a3 ? 1.f : 0.f; sw = a3 ? 0.f : sw; sw = fmaxf(sw, -1.f);
        __builtin_nontemporal_store(o, &pd[(size_t)(120 + i) * (CHW / 4)]);
    }
}

extern "C" void kernel_launch(void* const* d_in, const int* in_sizes, int n_in,
                              void* d_out, int out_size, void* d_ws, size_t ws_size,
                              hipStream_t stream) {
    const float* x = (const float*)d_in[0];   // [128,16,64,64]
    const float* W = (const float*)d_in[1];   // [64,16,3,3]
    const float* b = (const float*)d_in[2];   // [64]
    float* out = (float*)d_out;               // [128,64,64,64]
    float* Wtr = (float*)d_ws;                // 16*16*40*4 = 40960 B

    const size_t CONV_BYTES = (size_t)T_STEPS * CHW * sizeof(float);  // 134 MB
    const size_t CONV_OFF   = 1u << 20;                               // 1 MB align
    const bool   big_ws     = ws_size >= CONV_OFF + CONV_BYTES;
    float* conv = big_ws ? (float*)((char*)d_ws + CONV_OFF) : out;

    transpose_w<<<36, 256, 0, stream>>>(W, Wtr);

    dim3 g1(8, 128);   // 8 tiles (4 row-bands x 2 col-halves) x 128 t = 1024 blocks
    spiking_conv_pass1<<<g1, 512, 0, stream>>>(x, Wtr, b, conv);

    spiking_scan_pass2<<<(CHW / 4) / 256, 256, 0, stream>>>(conv, out);
}

// Round 11
// 256.467 us; speedup vs baseline: 1.0670x; 1.0670x over previous
//
#include <hip/hip_runtime.h>

#define T_STEPS 128
#define CIN     16
#define HH      64
#define WW      64
#define COUT    64
#define HWSZ    (HH * WW)          // 4096
#define CHW     (COUT * HWSZ)      // 262144
#define XCHW    (CIN * HWSZ)       // 65536

// pass-1 (R7 config — measured best, 110.6 us): block = one t, 16x32 tile,
// all 64 co. 8 waves; wave owns an 8-co set (72 w floats/ci via s_load).
// Thread = 1x8 spatial patch, ky-major (one 10-float LDS row live).
// HARD CONSTRAINT (R8/R9/R10): unified regs = 64 VGPR + 64 AGPR(acc) = 128
// exactly -> 2 blocks/CU. Any added VGPR pressure tips the cliff (R9: 68
// VGPR -> 1 block/CU, -12 us; R8: forced 85-reg cap -> scratch spill, -196 us;
// R10: unroll 2 -> compiler re-squeeze to 60 VGPR, -3 us). Do not perturb.
#define TILEH   16
#define TILEW   32
#define HALOH   18
#define HALOW   34
#define LSTR    36                    // padded LDS row stride (floats)
#define PLANE   (HALOH * LSTR)        // 648 floats per ci
#define NST     (CIN * HALOH * HALOW) // 9792 staged elements
#define WBLK    40                    // padded weight block per (co-group-of-4, ci)

typedef float vfloat4 __attribute__((ext_vector_type(4)));  // native vec for NT store

// ---- setup: W[64][16][3][3] -> Wtr[(co>>2)*16+ci][40], inner (co&3)*9+k ----
__global__ void transpose_w(const float* __restrict__ W, float* __restrict__ Wtr) {
    int e = blockIdx.x * 256 + threadIdx.x;     // 0..9215
    if (e >= COUT * CIN * 9) return;
    int co = e / (CIN * 9);
    int r  = e - co * (CIN * 9);
    int ci = r / 9;
    int k  = r - ci * 9;
    Wtr[((co >> 2) * CIN + ci) * WBLK + (co & 3) * 9 + k] = W[e];
}

__global__ __launch_bounds__(512, 2)
void spiking_conv_pass1(const float* __restrict__ x, const float* __restrict__ Wtr,
                        const float* __restrict__ b, float* __restrict__ out) {
    __shared__ float xs[CIN * PLANE];   // 41472 B

    const int tid = threadIdx.x;        // 0..511
    const int t   = blockIdx.y;
    const int h0  = (blockIdx.x >> 1) * TILEH;   // 4 row-bands
    const int w0  = (blockIdx.x & 1) * TILEW;    // 2 col-halves

    // ---- stage all 16 ci (+halo) once: 9792 elements, 2 batches of 10 ----
    const float* xt = x + t * XCHW;
    {
        float vbuf[10]; int ibuf[10];
#pragma unroll
        for (int k = 0; k < 10; ++k) {
            unsigned e = tid + k * 512;
            unsigned ci = e / (HALOH * HALOW);
            unsigned rem = e - ci * (HALOH * HALOW);
            unsigned r  = rem / HALOW;
            unsigned c  = rem - r * HALOW;
            int gh = h0 - 1 + (int)r;
            int gw = w0 - 1 + (int)c;
            bool inb = (unsigned)gh < HH && (unsigned)gw < WW;
            vbuf[k] = inb ? xt[ci * HWSZ + gh * WW + gw] : 0.f;
            ibuf[k] = ci * PLANE + r * LSTR + c;
        }
#pragma unroll
        for (int k = 0; k < 10; ++k) xs[ibuf[k]] = vbuf[k];
#pragma unroll
        for (int k = 0; k < 10; ++k) {
            unsigned e = tid + (10 + k) * 512;
            unsigned ci = e / (HALOH * HALOW);
            unsigned rem = e - ci * (HALOH * HALOW);
            unsigned r  = rem / HALOW;
            unsigned c  = rem - r * HALOW;
            int gh = h0 - 1 + (int)r;
            int gw = w0 - 1 + (int)c;
            bool inb = e < NST && (unsigned)gh < HH && (unsigned)gw < WW;
            vbuf[k] = inb ? xt[ci * HWSZ + gh * WW + gw] : 0.f;
            ibuf[k] = (e < NST) ? (int)(ci * PLANE + r * LSTR + c) : -1;
        }
#pragma unroll
        for (int k = 0; k < 10; ++k)
            if (ibuf[k] >= 0) xs[ibuf[k]] = vbuf[k];
    }
    __syncthreads();

    // ---- compute: wave = one 8-co set; thread = 1x8 patch ----
    const int cog = __builtin_amdgcn_readfirstlane(tid >> 6);  // 0..7 (one per wave)
    const int ln  = tid & 63;
    const int pr0 = ln >> 2;            // 0..15
    const int pc0 = (ln & 3) * 8;       // 0,8,16,24
    float* outt = out + t * CHW;

    float acc[8][8];
#pragma unroll
    for (int j = 0; j < 8; ++j)
#pragma unroll
        for (int p = 0; p < 8; ++p) acc[j][p] = 0.f;

#pragma unroll 1
    for (int ci = 0; ci < CIN; ++ci) {
        // both 36-float w blocks for this wave's 8 co: SGPR-resident,
        // s_loads issued up front, hidden under the ky=0 FMAs.
        const float* wb0 = Wtr + ((cog * 2 + 0) * CIN + ci) * WBLK;
        const float* wb1 = Wtr + ((cog * 2 + 1) * CIN + ci) * WBLK;
        float w0[36], w1[36];
#pragma unroll
        for (int i = 0; i < 36; ++i) w0[i] = wb0[i];
#pragma unroll
        for (int i = 0; i < 36; ++i) w1[i] = wb1[i];

        // ky-major: one LDS row (10 floats) live at a time. Accumulate order
        // per output is (ci, ky, kx) -> bit-identical to reference order.
#pragma unroll
        for (int ky = 0; ky < 3; ++ky) {
            const float* row = &xs[ci * PLANE + (pr0 + ky) * LSTR + pc0];
            float4 a  = *(const float4*)row;
            float4 b4 = *(const float4*)(row + 4);
            float2 c2 = *(const float2*)(row + 8);
            float xv[10];
            xv[0] = a.x;  xv[1] = a.y;  xv[2] = a.z;  xv[3] = a.w;
            xv[4] = b4.x; xv[5] = b4.y; xv[6] = b4.z; xv[7] = b4.w;
            xv[8] = c2.x; xv[9] = c2.y;
#pragma unroll
            for (int jj = 0; jj < 4; ++jj)
#pragma unroll
                for (int kx = 0; kx < 3; ++kx) {
                    const float wv = w0[jj * 9 + ky * 3 + kx];
#pragma unroll
                    for (int p = 0; p < 8; ++p)
                        acc[jj][p] += wv * xv[kx + p];
                }
#pragma unroll
            for (int jj = 0; jj < 4; ++jj)
#pragma unroll
                for (int kx = 0; kx < 3; ++kx) {
                    const float wv = w1[jj * 9 + ky * 3 + kx];
#pragma unroll
                    for (int p = 0; p < 8; ++p)
                        acc[4 + jj][p] += wv * xv[kx + p];
                }
        }
    }

    // ---- epilogue: +bias, 2x float4 stores per co ----
#pragma unroll
    for (int g = 0; g < 2; ++g)
#pragma unroll
        for (int jj = 0; jj < 4; ++jj) {
            const int co = cog * 8 + g * 4 + jj;
            const float bias = b[co];
            float* op = &outt[co * HWSZ + (h0 + pr0) * WW + (w0 + pc0)];
            float4 o0, o1;
            o0.x = acc[g * 4 + jj][0] + bias;
            o0.y = acc[g * 4 + jj][1] + bias;
            o0.z = acc[g * 4 + jj][2] + bias;
            o0.w = acc[g * 4 + jj][3] + bias;
            o1.x = acc[g * 4 + jj][4] + bias;
            o1.y = acc[g * 4 + jj][5] + bias;
            o1.z = acc[g * 4 + jj][6] + bias;
            o1.w = acc[g * 4 + jj][7] + bias;
            *(float4*)op = o0;
            *(float4*)(op + 4) = o1;
        }
}

// Scan (R6/R7 config — measured best): float4-batch columns, out-of-place,
// REGULAR loads (pass1 just wrote conv; reads hit L2/L3 — NT loads measured
// +15 us in R10 by forcing HBM), NT stores for spikes (never re-read).
// src==dst stays the safe in-place fallback.
__global__ __launch_bounds__(256)
void spiking_scan_pass2(const float* __restrict__ src, float* __restrict__ dst) {
    const int idx = blockIdx.x * 256 + threadIdx.x;   // 0..65535
    const float4* ps = (const float4*)src + idx;      // column stride CHW/4
    vfloat4* pd = (vfloat4*)dst + idx;
    float sx = 0.f, sy = 0.f, sz = 0.f, sw = 0.f;
    float4 v[8], nv[8];
#pragma unroll
    for (int i = 0; i < 8; ++i) v[i] = ps[(size_t)i * (CHW / 4)];
#pragma unroll 1
    for (int tb = 0; tb < 15; ++tb) {
#pragma unroll
        for (int i = 0; i < 8; ++i) nv[i] = ps[(size_t)((tb + 1) * 8 + i) * (CHW / 4)];
#pragma unroll
        for (int i = 0; i < 8; ++i) {
            vfloat4 o;
            sx += v[i].x; bool a0 = (sx >= 8.0f); o.x = a0 ? 1.f : 0.f; sx = a0 ? 0.f : sx; sx = fmaxf(sx, -1.f);
            sy += v[i].y; bool a1 = (sy >= 8.0f); o.y = a1 ? 1.f : 0.f; sy = a1 ? 0.f : sy; sy = fmaxf(sy, -1.f);
            sz += v[i].z; bool a2 = (sz >= 8.0f); o.z = a2 ? 1.f : 0.f; sz = a2 ? 0.f : sz; sz = fmaxf(sz, -1.f);
            sw += v[i].w; bool a3 = (sw >= 8.0f); o.w = a3 ? 1.f : 0.f; sw = a3 ? 0.f : sw; sw = fmaxf(sw, -1.f);
            __builtin_nontemporal_store(o, &pd[(size_t)(tb * 8 + i) * (CHW / 4)]);
        }
#pragma unroll
        for (int i = 0; i < 8; ++i) v[i] = nv[i];
    }
#pragma unroll
    for (int i = 0; i < 8; ++i) {
        vfloat4 o;
        sx += v[i].x; bool a0 = (sx >= 8.0f); o.x = a0 ? 1.f : 0.f; sx = a0 ? 0.f : sx; sx = fmaxf(sx, -1.f);
        sy += v[i].y; bool a1 = (sy >= 8.0f); o.y = a1 ? 1.f : 0.f; sy = a1 ? 0.f : sy; sy = fmaxf(sy, -1.f);
        sz += v[i].z; bool a2 = (sz >= 8.0f); o.z = a2 ? 1.f : 0.f; sz = a2 ? 0.f : sz; sz = fmaxf(sz, -1.f);
        sw += v[i].w; bool a3 = (sw >= 8.0f); o.w = a3 ? 1.f : 0.f; sw = a3 ? 0.f : sw; sw = fmaxf(sw, -1.f);
        __builtin_nontemporal_store(o, &pd[(size_t)(120 + i) * (CHW / 4)]);
    }
}

extern "C" void kernel_launch(void* const* d_in, const int* in_sizes, int n_in,
                              void* d_out, int out_size, void* d_ws, size_t ws_size,
                              hipStream_t stream) {
    const float* x = (const float*)d_in[0];   // [128,16,64,64]
    const float* W = (const float*)d_in[1];   // [64,16,3,3]
    const float* b = (const float*)d_in[2];   // [64]
    float* out = (float*)d_out;               // [128,64,64,64]
    float* Wtr = (float*)d_ws;                // 16*16*40*4 = 40960 B

    const size_t CONV_BYTES = (size_t)T_STEPS * CHW * sizeof(float);  // 134 MB
    const size_t CONV_OFF   = 1u << 20;                               // 1 MB align
    const bool   big_ws     = ws_size >= CONV_OFF + CONV_BYTES;
    float* conv = big_ws ? (float*)((char*)d_ws + CONV_OFF) : out;

    transpose_w<<<36, 256, 0, stream>>>(W, Wtr);

    dim3 g1(8, 128);   // 8 tiles (4 row-bands x 2 col-halves) x 128 t = 1024 blocks
    spiking_conv_pass1<<<g1, 512, 0, stream>>>(x, Wtr, b, conv);

    spiking_scan_pass2<<<(CHW / 4) / 256, 256, 0, stream>>>(conv, out);
}

// Round 12
// 254.987 us; speedup vs baseline: 1.0732x; 1.0058x over previous
//
#include <hip/hip_runtime.h>

#define T_STEPS 128
#define CIN     16
#define HH      64
#define WW      64
#define COUT    64
#define HWSZ    (HH * WW)          // 4096
#define CHW     (COUT * HWSZ)      // 262144
#define XCHW    (CIN * HWSZ)       // 65536

// pass-1 (R7 config — measured best): block = one t, 16x32 tile, all 64 co.
// 8 waves; wave owns an 8-co set (72 w floats/ci via s_load). Thread = 1x8
// spatial patch, ky-major (one 10-float LDS row live).
// HARD CONSTRAINT (R8/R9/R10): unified regs = 64 VGPR + 64 AGPR(acc) = 128
// exactly -> 2 blocks/CU. Any added VGPR pressure tips the cliff. Do not
// perturb register pressure.
// NEW (R12): s_setprio(1) around the ci loop — waves are desynchronized
// after the single barrier; at block transitions, staging waves (VMEM+index
// VALU) share SIMDs with compute waves (pure FMA). Prio biases issue toward
// FMA waves (T5/m191 structure: independent waves -> setprio pays).
#define TILEH   16
#define TILEW   32
#define HALOH   18
#define HALOW   34
#define LSTR    36                    // padded LDS row stride (floats)
#define PLANE   (HALOH * LSTR)        // 648 floats per ci
#define NST     (CIN * HALOH * HALOW) // 9792 staged elements
#define WBLK    40                    // padded weight block per (co-group-of-4, ci)

typedef float vfloat4 __attribute__((ext_vector_type(4)));  // native vec for NT store

// ---- setup: W[64][16][3][3] -> Wtr[(co>>2)*16+ci][40], inner (co&3)*9+k ----
__global__ void transpose_w(const float* __restrict__ W, float* __restrict__ Wtr) {
    int e = blockIdx.x * 256 + threadIdx.x;     // 0..9215
    if (e >= COUT * CIN * 9) return;
    int co = e / (CIN * 9);
    int r  = e - co * (CIN * 9);
    int ci = r / 9;
    int k  = r - ci * 9;
    Wtr[((co >> 2) * CIN + ci) * WBLK + (co & 3) * 9 + k] = W[e];
}

__global__ __launch_bounds__(512, 2)
void spiking_conv_pass1(const float* __restrict__ x, const float* __restrict__ Wtr,
                        const float* __restrict__ b, float* __restrict__ out) {
    __shared__ float xs[CIN * PLANE];   // 41472 B

    const int tid = threadIdx.x;        // 0..511
    const int t   = blockIdx.y;
    const int h0  = (blockIdx.x >> 1) * TILEH;   // 4 row-bands
    const int w0  = (blockIdx.x & 1) * TILEW;    // 2 col-halves

    // ---- stage all 16 ci (+halo) once: 9792 elements, 2 batches of 10 ----
    const float* xt = x + t * XCHW;
    {
        float vbuf[10]; int ibuf[10];
#pragma unroll
        for (int k = 0; k < 10; ++k) {
            unsigned e = tid + k * 512;
            unsigned ci = e / (HALOH * HALOW);
            unsigned rem = e - ci * (HALOH * HALOW);
            unsigned r  = rem / HALOW;
            unsigned c  = rem - r * HALOW;
            int gh = h0 - 1 + (int)r;
            int gw = w0 - 1 + (int)c;
            bool inb = (unsigned)gh < HH && (unsigned)gw < WW;
            vbuf[k] = inb ? xt[ci * HWSZ + gh * WW + gw] : 0.f;
            ibuf[k] = ci * PLANE + r * LSTR + c;
        }
#pragma unroll
        for (int k = 0; k < 10; ++k) xs[ibuf[k]] = vbuf[k];
#pragma unroll
        for (int k = 0; k < 10; ++k) {
            unsigned e = tid + (10 + k) * 512;
            unsigned ci = e / (HALOH * HALOW);
            unsigned rem = e - ci * (HALOH * HALOW);
            unsigned r  = rem / HALOW;
            unsigned c  = rem - r * HALOW;
            int gh = h0 - 1 + (int)r;
            int gw = w0 - 1 + (int)c;
            bool inb = e < NST && (unsigned)gh < HH && (unsigned)gw < WW;
            vbuf[k] = inb ? xt[ci * HWSZ + gh * WW + gw] : 0.f;
            ibuf[k] = (e < NST) ? (int)(ci * PLANE + r * LSTR + c) : -1;
        }
#pragma unroll
        for (int k = 0; k < 10; ++k)
            if (ibuf[k] >= 0) xs[ibuf[k]] = vbuf[k];
    }
    __syncthreads();

    // ---- compute: wave = one 8-co set; thread = 1x8 patch ----
    const int cog = __builtin_amdgcn_readfirstlane(tid >> 6);  // 0..7 (one per wave)
    const int ln  = tid & 63;
    const int pr0 = ln >> 2;            // 0..15
    const int pc0 = (ln & 3) * 8;       // 0,8,16,24
    float* outt = out + t * CHW;

    float acc[8][8];
#pragma unroll
    for (int j = 0; j < 8; ++j)
#pragma unroll
        for (int p = 0; p < 8; ++p) acc[j][p] = 0.f;

    __builtin_amdgcn_s_setprio(1);      // favor FMA waves over staging waves

#pragma unroll 1
    for (int ci = 0; ci < CIN; ++ci) {
        // both 36-float w blocks for this wave's 8 co: SGPR-resident,
        // s_loads issued up front, hidden under the ky=0 FMAs.
        const float* wb0 = Wtr + ((cog * 2 + 0) * CIN + ci) * WBLK;
        const float* wb1 = Wtr + ((cog * 2 + 1) * CIN + ci) * WBLK;
        float w0[36], w1[36];
#pragma unroll
        for (int i = 0; i < 36; ++i) w0[i] = wb0[i];
#pragma unroll
        for (int i = 0; i < 36; ++i) w1[i] = wb1[i];

        // ky-major: one LDS row (10 floats) live at a time. Accumulate order
        // per output is (ci, ky, kx) -> bit-identical to reference order.
#pragma unroll
        for (int ky = 0; ky < 3; ++ky) {
            const float* row = &xs[ci * PLANE + (pr0 + ky) * LSTR + pc0];
            float4 a  = *(const float4*)row;
            float4 b4 = *(const float4*)(row + 4);
            float2 c2 = *(const float2*)(row + 8);
            float xv[10];
            xv[0] = a.x;  xv[1] = a.y;  xv[2] = a.z;  xv[3] = a.w;
            xv[4] = b4.x; xv[5] = b4.y; xv[6] = b4.z; xv[7] = b4.w;
            xv[8] = c2.x; xv[9] = c2.y;
#pragma unroll
            for (int jj = 0; jj < 4; ++jj)
#pragma unroll
                for (int kx = 0; kx < 3; ++kx) {
                    const float wv = w0[jj * 9 + ky * 3 + kx];
#pragma unroll
                    for (int p = 0; p < 8; ++p)
                        acc[jj][p] += wv * xv[kx + p];
                }
#pragma unroll
            for (int jj = 0; jj < 4; ++jj)
#pragma unroll
                for (int kx = 0; kx < 3; ++kx) {
                    const float wv = w1[jj * 9 + ky * 3 + kx];
#pragma unroll
                    for (int p = 0; p < 8; ++p)
                        acc[4 + jj][p] += wv * xv[kx + p];
                }
        }
    }

    __builtin_amdgcn_s_setprio(0);      // epilogue/staging back to normal

    // ---- epilogue: +bias, 2x float4 stores per co ----
#pragma unroll
    for (int g = 0; g < 2; ++g)
#pragma unroll
        for (int jj = 0; jj < 4; ++jj) {
            const int co = cog * 8 + g * 4 + jj;
            const float bias = b[co];
            float* op = &outt[co * HWSZ + (h0 + pr0) * WW + (w0 + pc0)];
            float4 o0, o1;
            o0.x = acc[g * 4 + jj][0] + bias;
            o0.y = acc[g * 4 + jj][1] + bias;
            o0.z = acc[g * 4 + jj][2] + bias;
            o0.w = acc[g * 4 + jj][3] + bias;
            o1.x = acc[g * 4 + jj][4] + bias;
            o1.y = acc[g * 4 + jj][5] + bias;
            o1.z = acc[g * 4 + jj][6] + bias;
            o1.w = acc[g * 4 + jj][7] + bias;
            *(float4*)op = o0;
            *(float4*)(op + 4) = o1;
        }
}

// Scan (measured best): float4-batch columns, out-of-place, REGULAR loads
// (reads hit L2/L3 — NT loads measured +15 us in R10 by forcing HBM), NT
// stores for spikes (never re-read). src==dst is the safe in-place fallback.
__global__ __launch_bounds__(256)
void spiking_scan_pass2(const float* __restrict__ src, float* __restrict__ dst) {
    const int idx = blockIdx.x * 256 + threadIdx.x;   // 0..65535
    const float4* ps = (const float4*)src + idx;      // column stride CHW/4
    vfloat4* pd = (vfloat4*)dst + idx;
    float sx = 0.f, sy = 0.f, sz = 0.f, sw = 0.f;
    float4 v[8], nv[8];
#pragma unroll
    for (int i = 0; i < 8; ++i) v[i] = ps[(size_t)i * (CHW / 4)];
#pragma unroll 1
    for (int tb = 0; tb < 15; ++tb) {
#pragma unroll
        for (int i = 0; i < 8; ++i) nv[i] = ps[(size_t)((tb + 1) * 8 + i) * (CHW / 4)];
#pragma unroll
        for (int i = 0; i < 8; ++i) {
            vfloat4 o;
            sx += v[i].x; bool a0 = (sx >= 8.0f); o.x = a0 ? 1.f : 0.f; sx = a0 ? 0.f : sx; sx = fmaxf(sx, -1.f);
            sy += v[i].y; bool a1 = (sy >= 8.0f); o.y = a1 ? 1.f : 0.f; sy = a1 ? 0.f : sy; sy = fmaxf(sy, -1.f);
            sz += v[i].z; bool a2 = (sz >= 8.0f); o.z = a2 ? 1.f : 0.f; sz = a2 ? 0.f : sz; sz = fmaxf(sz, -1.f);
            sw += v[i].w; bool a3 = (sw >= 8.0f); o.w = a3 ? 1.f : 0.f; sw = a3 ? 0.f : sw; sw = fmaxf(sw, -1.f);
            __builtin_nontemporal_store(o, &pd[(size_t)(tb * 8 + i) * (CHW / 4)]);
        }
#pragma unroll
        for (int i = 0; i < 8; ++i) v[i] = nv[i];
    }
#pragma unroll
    for (int i = 0; i < 8; ++i) {
        vfloat4 o;
        sx += v[i].x; bool a0 = (sx >= 8.0f); o.x = a0 ? 1.f : 0.f; sx = a0 ? 0.f : sx; sx = fmaxf(sx, -1.f);
        sy += v[i].y; bool a1 = (sy >= 8.0f); o.y = a1 ? 1.f : 0.f; sy = a1 ? 0.f : sy; sy = fmaxf(sy, -1.f);
        sz += v[i].z; bool a2 = (sz >= 8.0f); o.z = a2 ? 1.f : 0.f; sz = a2 ? 0.f : sz; sz = fmaxf(sz, -1.f);
        sw += v[i].w; bool a3 = (sw >= 8.0f); o.w = a3 ? 1.f : 0.f; sw = a3 ? 0.f : sw; sw = fmaxf(sw, -1.f);
        __builtin_nontemporal_store(o, &pd[(size_t)(120 + i) * (CHW / 4)]);
    }
}

extern "C" void kernel_launch(void* const* d_in, const int* in_sizes, int n_in,
                              void* d_out, int out_size, void* d_ws, size_t ws_size,
                              hipStream_t stream) {
    const float* x = (const float*)d_in[0];   // [128,16,64,64]
    const float* W = (const float*)d_in[1];   // [64,16,3,3]
    const float* b = (const float*)d_in[2];   // [64]
    float* out = (float*)d_out;               // [128,64,64,64]
    float* Wtr = (float*)d_ws;                // 16*16*40*4 = 40960 B

    const size_t CONV_BYTES = (size_t)T_STEPS * CHW * sizeof(float);  // 134 MB
    const size_t CONV_OFF   = 1u << 20;                               // 1 MB align
    const bool   big_ws     = ws_size >= CONV_OFF + CONV_BYTES;
    float* conv = big_ws ? (float*)((char*)d_ws + CONV_OFF) : out;

    transpose_w<<<36, 256, 0, stream>>>(W, Wtr);

    dim3 g1(8, 128);   // 8 tiles (4 row-bands x 2 col-halves) x 128 t = 1024 blocks
    spiking_conv_pass1<<<g1, 512, 0, stream>>>(x, Wtr, b, conv);

    spiking_scan_pass2<<<(CHW / 4) / 256, 256, 0, stream>>>(conv, out);
}